// Round 3
// baseline (1610.673 us; speedup 1.0000x reference)
//
#include <hip/hip_runtime.h>
#include <stdint.h>

typedef __bf16 bf16_t;
typedef __bf16 bf16x8 __attribute__((ext_vector_type(8)));
typedef float f32x4 __attribute__((ext_vector_type(4)));

#define MFMA16(a, b, c) __builtin_amdgcn_mfma_f32_16x16x32_bf16(a, b, c, 0, 0, 0)

__device__ __forceinline__ void gload_lds16(const bf16_t* g, bf16_t* l) {
  __builtin_amdgcn_global_load_lds(
      (const __attribute__((address_space(1))) void*)g,
      (__attribute__((address_space(3))) void*)l, 16, 0, 0);
}

__device__ __forceinline__ int sw4(int i) {  // nibble swap of 0..15
  return ((i & 3) << 2) | ((i >> 2) & 3);
}

// ---------------------------------------------------------------------------
// Convert x fp32 -> bf16, 8 elements/thread.
__global__ __launch_bounds__(256) void cvt_x_k(const float* __restrict__ x,
                                               bf16_t* __restrict__ xb, int n8) {
  int i = blockIdx.x * 256 + threadIdx.x;
  if (i >= n8) return;
  const float4* xp = (const float4*)x + (size_t)i * 2;
  float4 f0 = xp[0], f1 = xp[1];
  bf16x8 o = {(bf16_t)f0.x, (bf16_t)f0.y, (bf16_t)f0.z, (bf16_t)f0.w,
              (bf16_t)f1.x, (bf16_t)f1.y, (bf16_t)f1.z, (bf16_t)f1.w};
  *(bf16x8*)(xb + (size_t)i * 8) = o;
}

// Transpose+convert both weights in one launch. blocks 0..767: qkv_w [256,768];
// blocks 768..1023: proj_w [256,256].
__global__ __launch_bounds__(256) void cvt_w2_k(const float* __restrict__ w1,
                                                bf16_t* __restrict__ o1,
                                                const float* __restrict__ w2,
                                                bf16_t* __restrict__ o2) {
  int blk = blockIdx.x, k = threadIdx.x;
  if (blk < 768) {
    o1[(size_t)blk * 256 + k] = (bf16_t)w1[(size_t)k * 768 + blk];
  } else {
    int n = blk - 768;
    o2[(size_t)n * 256 + k] = (bf16_t)w2[(size_t)k * 256 + n];
  }
}

// ---------------------------------------------------------------------------
// GEMM: C[M, ncols-slice] = A[M,256] @ B  with BT[n][k] pre-transposed bf16.
// XCD chunk-swizzle (bijective, nwg%8==0): each XCD owns a contiguous run of
// tile-space, so the n-tiles sharing one A panel hit the same L2.
__global__ __launch_bounds__(256) void gemm256(const bf16_t* __restrict__ A,
                                               const bf16_t* __restrict__ BT,
                                               int ncols,
                                               bf16_t* __restrict__ outb,
                                               float* __restrict__ outf,
                                               const float* __restrict__ bias) {
  __shared__ __align__(16) bf16_t sA[128 * 64];
  __shared__ __align__(16) bf16_t sB[128 * 64];
  const int tid = threadIdx.x;
  const int lane = tid & 63, wave = tid >> 6;
  const int lm = lane & 15, quad = lane >> 4;

  int nwg = gridDim.x * gridDim.y;
  int L = blockIdx.y * gridDim.x + blockIdx.x;
  if ((nwg & 7) == 0) {
    int cpx = nwg >> 3;
    L = (L & 7) * cpx + (L >> 3);
  }
  const int bx = L % gridDim.x, by = L / gridDim.x;

  const int mBase = by * 128;
  const int nBase = bx * 128;
  const int wm = (wave >> 1) * 64, wn = (wave & 1) * 64;

  f32x4 acc[4][4];
#pragma unroll
  for (int i = 0; i < 4; i++)
#pragma unroll
    for (int j = 0; j < 4; j++) acc[i][j] = {0.f, 0.f, 0.f, 0.f};

  const bf16_t* Ab = A + (size_t)mBase * 256;
  const bf16_t* Bb = BT + (size_t)nBase * 256;

  for (int kb = 0; kb < 4; ++kb) {
    const int k0 = kb * 64;
#pragma unroll
    for (int it = 0; it < 4; ++it) {
      int cid = it * 256 + wave * 64 + lane;
      int row = cid >> 3, kcp = cid & 7;
      int kcl = kcp ^ (row & 7);
      bf16_t* dstA = sA + (it * 256 + wave * 64) * 8;  // wave-uniform base
      bf16_t* dstB = sB + (it * 256 + wave * 64) * 8;
      gload_lds16(Ab + (size_t)row * 256 + k0 + kcl * 8, dstA);
      gload_lds16(Bb + (size_t)row * 256 + k0 + kcl * 8, dstB);
    }
    __syncthreads();
#pragma unroll
    for (int kk = 0; kk < 64; kk += 32) {
      int c = (kk >> 3) + quad;
      bf16x8 af[4], bfr[4];
#pragma unroll
      for (int mt = 0; mt < 4; mt++) {
        int m = wm + mt * 16 + lm;
        af[mt] = *(const bf16x8*)(sA + m * 64 + ((c ^ (m & 7)) << 3));
      }
#pragma unroll
      for (int nt = 0; nt < 4; nt++) {
        int n = wn + nt * 16 + lm;
        bfr[nt] = *(const bf16x8*)(sB + n * 64 + ((c ^ (n & 7)) << 3));
      }
#pragma unroll
      for (int mt = 0; mt < 4; mt++)
#pragma unroll
        for (int nt = 0; nt < 4; nt++)
          acc[mt][nt] = MFMA16(af[mt], bfr[nt], acc[mt][nt]);
    }
    __syncthreads();
  }

  if (outb) {
#pragma unroll
    for (int mt = 0; mt < 4; mt++)
#pragma unroll
      for (int nt = 0; nt < 4; nt++) {
        int col = nBase + wn + nt * 16 + lm;
        int rbase = mBase + wm + mt * 16 + quad * 4;
#pragma unroll
        for (int r = 0; r < 4; r++)
          outb[(size_t)(rbase + r) * ncols + col] = (bf16_t)acc[mt][nt][r];
      }
  } else {
#pragma unroll
    for (int mt = 0; mt < 4; mt++)
#pragma unroll
      for (int nt = 0; nt < 4; nt++) {
        int col = nBase + wn + nt * 16 + lm;
        float bv = bias[col];
        int rbase = mBase + wm + mt * 16 + quad * 4;
#pragma unroll
        for (int r = 0; r < 4; r++)
          outf[(size_t)(rbase + r) * ncols + col] = acc[mt][nt][r] + bv;
      }
  }
}

// ---------------------------------------------------------------------------
// Fused window attention, v5: head-pair per block + 8-deep b-pipeline.
// 512 threads = 8 waves; waves 0-3 head 2p, waves 4-7 head 2p+1 (w4 = wave&3).
// Block (p, by) iterates b = by + 256*it, it=0..7. Mask window (b&63 = by&63)
// is CONSTANT per block -> its 38KB mask slice stays L1/L2-hot.
// Pipeline: qf/vv prefetched for b+1 right after QK^T consumes them; kf after
// softmax. All prefetches sit inside the (syncA, syncB) window so the
// __syncthreads vmcnt(0) drain coincides with when the data is needed.
// 2 barriers/iter: scatter->PV(sVT) and PV->next-scatter. P-store->PV needs
// none (sP rows are wave-partitioned; within-wave lgkmcnt ordering suffices).
// asm-opaque on epilogue indices defeats LICM of the loop-invariant mask/bias
// loads (would otherwise hoist ~112 values into registers and spill).
__global__ __launch_bounds__(512, 4) void attn_win(
    const bf16_t* __restrict__ qkv, const float* __restrict__ mask,
    const float* __restrict__ btab, bf16_t* __restrict__ y) {
  __shared__ __align__(16) bf16_t sP[2][112 * 128];
  __shared__ __align__(16) bf16_t sVT[2][32 * 128];
  __shared__ float sTab[2][512];
  __shared__ int sU[112];

  const int tid = threadIdx.x;
  const int p = blockIdx.x, by = blockIdx.y;
  const int lane = tid & 63, wave = tid >> 6;
  const int w4 = wave & 3, hg = wave >> 2;
  const int h = 2 * p + hg;
  const int lm = lane & 15, quad = lane >> 4;
  const int sj = tid & 127, sq2 = (tid >> 7) & 1, sg = tid >> 8;

  // ---- one-time LDS setup ----
  {
    uint4 z = {0, 0, 0, 0};
    uint4* pp = (uint4*)&sP[0][0];
    for (int i = tid; i < 2 * 112 * 128 / 8; i += 512) pp[i] = z;
  }
  for (int idx = tid; idx < 2048; idx += 512) {
    int g = idx >> 10, r = idx & 1023;
    int d = r >> 5, j = 96 + (r & 31);
    if (j >= 98)
      sVT[g][d * 128 + (((j >> 3) ^ sw4(d & 15)) << 3) + (j & 7)] = (bf16_t)0.f;
  }
  for (int idx = tid; idx < 1024; idx += 512) {
    int g = idx >> 9, i2 = idx & 511;
    if (i2 < 507) sTab[g][i2] = btab[i2 * 8 + 2 * p + g];
  }
  if (tid < 112) {
    int n = tid;
    int d = n / 49, r = n - d * 49;
    int hh = r / 7, w = r - hh * 7;
    sU[tid] = (n < 98) ? (d * 169 + hh * 13 + w) : 0;
  }

  const size_t bstr = 98 * 768;
  const bf16_t* qh = qkv + (size_t)by * bstr + h * 32;
  const bf16_t* qv = qkv + (size_t)by * bstr + (2 * p + sg) * 32;

  // ---- prologue loads for b = by (overlap the LDS setup) ----
  bf16x8 kf[7], qf[2], vv[2];
#pragma unroll
  for (int ct = 0; ct < 7; ct++)
    kf[ct] =
        *(const bf16x8*)(qh + (size_t)(ct * 16 + lm) * 768 + 256 + quad * 8);
  qf[0] = *(const bf16x8*)(qh + (size_t)(w4 * 16 + lm) * 768 + quad * 8);
  if (w4 < 3)
    qf[1] =
        *(const bf16x8*)(qh + (size_t)((w4 + 4) * 16 + lm) * 768 + quad * 8);
  if (sj < 98) {
    vv[0] = *(const bf16x8*)(qv + (size_t)sj * 768 + 512 + sq2 * 8);
    vv[1] = *(const bf16x8*)(qv + (size_t)sj * 768 + 512 + (sq2 + 2) * 8);
  }

  __syncthreads();  // setup visible (sU/sTab/sP zeros/sVT pads)

  // ---- loop-invariant epilogue indices (all b-independent) ----
  const float* mp = mask + (size_t)(by & 63) * 9604;
  const float scale = 0.17677669529663687f;
  int uj7[7];
#pragma unroll
  for (int ct = 0; ct < 7; ct++) uj7[ct] = sU[ct * 16 + lm];
  int ui_[2][4], rbo[2][4];
#pragma unroll
  for (int rti = 0; rti < 2; rti++) {
    if (rti == 1 && w4 == 3) continue;
    int rt = w4 + rti * 4;
    int ib = rt * 16 + quad * 4;
#pragma unroll
    for (int r = 0; r < 4; r++) {
      int i = ib + r;
      ui_[rti][r] = sU[i] + 253;
      rbo[rti][r] = (i < 98 ? i : 97) * 98;
    }
  }

  int bcur = by;
  for (int it2 = 0; it2 < 8; ++it2) {
    const bool more = (it2 < 7);
    const bf16_t* qhn = qh + 256 * bstr;
    const bf16_t* qvn = qv + 256 * bstr;

    // defeat LICM of mask/bias loads across the b-loop
#pragma unroll
    for (int rti = 0; rti < 2; rti++) {
      if (rti == 1 && w4 == 3) continue;
#pragma unroll
      for (int r = 0; r < 4; r++) {
        asm volatile("" : "+v"(ui_[rti][r]));
        asm volatile("" : "+v"(rbo[rti][r]));
      }
    }

    // ---- V scatter (consumes vv) ----
    if (sj < 98) {
#pragma unroll
      for (int t = 0; t < 2; t++) {
        int dc = sq2 + 2 * t;
#pragma unroll
        for (int e = 0; e < 8; e++) {
          int d = dc * 8 + e;
          sVT[sg][d * 128 + (((sj >> 3) ^ sw4(d & 15)) << 3) + (sj & 7)] =
              vv[t][e];
        }
      }
    }
    __syncthreads();  // syncA: sVT ready; no vm loads outstanding here

    // ---- QK^T (consumes qf, kf) ----
    f32x4 s4[2][7];
#pragma unroll
    for (int rti = 0; rti < 2; rti++) {
      if (rti == 1 && w4 == 3) continue;
#pragma unroll
      for (int ct = 0; ct < 7; ct++) {
        f32x4 z = {0.f, 0.f, 0.f, 0.f};
        s4[rti][ct] = MFMA16(qf[rti], kf[ct], z);
      }
    }

    // ---- prefetch vv, qf for b+256 (post-consumption; in-flight thru PV) --
    if (more) {
      if (sj < 98) {
        vv[0] = *(const bf16x8*)(qvn + (size_t)sj * 768 + 512 + sq2 * 8);
        vv[1] = *(const bf16x8*)(qvn + (size_t)sj * 768 + 512 + (sq2 + 2) * 8);
      }
      qf[0] = *(const bf16x8*)(qhn + (size_t)(w4 * 16 + lm) * 768 + quad * 8);
      if (w4 < 3)
        qf[1] = *(const bf16x8*)(qhn + (size_t)((w4 + 4) * 16 + lm) * 768 +
                                 quad * 8);
    }

    // ---- epilogue: scale + bias + mask; softmax ----
    float inv[2][4];
#pragma unroll
    for (int rti = 0; rti < 2; rti++) {
      if (rti == 1 && w4 == 3) continue;
#pragma unroll
      for (int ct = 0; ct < 7; ct++) {
        int j = ct * 16 + lm;
        int jc = j < 98 ? j : 97;
        bool jv = j < 98;
#pragma unroll
        for (int r = 0; r < 4; r++) {
          float v = s4[rti][ct][r] * scale +
                    sTab[hg][ui_[rti][r] - uj7[ct]] + mp[rbo[rti][r] + jc];
          s4[rti][ct][r] = jv ? v : -1e30f;
        }
      }
#pragma unroll
      for (int r = 0; r < 4; r++) {
        float mx = s4[rti][0][r];
#pragma unroll
        for (int ct = 1; ct < 7; ct++) mx = fmaxf(mx, s4[rti][ct][r]);
#pragma unroll
        for (int o = 1; o < 16; o <<= 1) mx = fmaxf(mx, __shfl_xor(mx, o));
        float sum = 0.f;
#pragma unroll
        for (int ct = 0; ct < 7; ct++) {
          float e = __expf(s4[rti][ct][r] - mx);
          s4[rti][ct][r] = e;
          sum += e;
        }
#pragma unroll
        for (int o = 1; o < 16; o <<= 1) sum += __shfl_xor(sum, o);
        inv[rti][r] = 1.f / sum;
      }
    }

    // ---- prefetch kf for b+256 (kf dead since QK^T) ----
    if (more) {
#pragma unroll
      for (int ct = 0; ct < 7; ct++)
        kf[ct] = *(const bf16x8*)(qhn + (size_t)(ct * 16 + lm) * 768 + 256 +
                                  quad * 8);
    }

    // ---- P stores (own-wave rows; no barrier before PV needed) ----
#pragma unroll
    for (int rti = 0; rti < 2; rti++) {
      if (rti == 1 && w4 == 3) continue;
      int rt = w4 + rti * 4;
      int ib = rt * 16 + quad * 4;
#pragma unroll
      for (int ct = 0; ct < 7; ct++) {
        int c2 = 2 * ct + (lm >> 3);
        int j7 = lm & 7;
#pragma unroll
        for (int r = 0; r < 4; r++) {
          int i = ib + r;
          sP[hg][i * 128 + ((c2 ^ (4 * r + quad)) << 3) + j7] =
              (bf16_t)s4[rti][ct][r];
        }
      }
    }

    // ---- O = P V ----
    bf16x8 vf2[2][4];
#pragma unroll
    for (int dt = 0; dt < 2; dt++)
#pragma unroll
      for (int kk = 0; kk < 4; kk++) {
        int d = dt * 16 + lm;
        vf2[dt][kk] = *(const bf16x8*)(sVT[hg] + d * 128 +
                                       (((4 * kk + quad) ^ sw4(lm)) << 3));
      }
    bf16_t* yb = y + (size_t)bcur * 98 * 256 + h * 32;
#pragma unroll
    for (int rti = 0; rti < 2; rti++) {
      if (rti == 1 && w4 == 3) continue;
      int rt = w4 + rti * 4;
      bf16x8 af[4];
#pragma unroll
      for (int kk = 0; kk < 4; kk++) {
        int i = rt * 16 + lm;
        af[kk] = *(const bf16x8*)(sP[hg] + i * 128 +
                                  (((4 * kk + quad) ^ sw4(lm)) << 3));
      }
#pragma unroll
      for (int dt = 0; dt < 2; dt++) {
        f32x4 o = {0.f, 0.f, 0.f, 0.f};
#pragma unroll
        for (int kk = 0; kk < 4; kk++) o = MFMA16(af[kk], vf2[dt][kk], o);
#pragma unroll
        for (int r = 0; r < 4; r++) {
          int i = rt * 16 + quad * 4 + r;
          if (i < 98)
            yb[(size_t)i * 256 + dt * 16 + lm] = (bf16_t)(o[r] * inv[rti][r]);
        }
      }
    }
    __syncthreads();  // syncB: drains prefetches (full window), guards sVT

    qh = qhn;
    qv = qvn;
    bcur += 256;
  }
}

// ---------------------------------------------------------------------------
extern "C" void kernel_launch(void* const* d_in, const int* in_sizes, int n_in,
                              void* d_out, int out_size, void* d_ws,
                              size_t ws_size, hipStream_t stream) {
  const float* x = (const float*)d_in[0];       // [2048, 98, 256]
  const float* mask = (const float*)d_in[1];    // [64, 98, 98]
  const float* qkv_w = (const float*)d_in[2];   // [256, 768]
  const float* proj_w = (const float*)d_in[3];  // [256, 256]
  const float* proj_b = (const float*)d_in[4];  // [256]
  const float* btab = (const float*)d_in[5];    // [507, 8]
  float* out = (float*)d_out;                   // [2048, 98, 256]

  char* ws = (char*)d_ws;
  bf16_t* qkv = (bf16_t*)ws;
  bf16_t* ybuf = (bf16_t*)(ws + 308281344);
  bf16_t* xb = ybuf;  // alias: consumed by gemm1 before attn writes y
  bf16_t* wT = (bf16_t*)(ws + 308281344 + 102760448);
  bf16_t* pT = (bf16_t*)(ws + 308281344 + 102760448 + 393216);

  cvt_x_k<<<25088, 256, 0, stream>>>(x, xb, 6422528);
  cvt_w2_k<<<1024, 256, 0, stream>>>(qkv_w, wT, proj_w, pT);

  gemm256<<<dim3(6, 1568), 256, 0, stream>>>(xb, wT, 768, qkv, nullptr,
                                             nullptr);

  attn_win<<<dim3(4, 256), 512, 0, stream>>>(qkv, mask, btab, ybuf);

  gemm256<<<dim3(2, 1568), 256, 0, stream>>>(ybuf, pT, 256, nullptr, out,
                                             proj_b);
}

// Round 4
// 729.104 us; speedup vs baseline: 2.2091x; 2.2091x over previous
//
#include <hip/hip_runtime.h>
#include <stdint.h>

typedef __bf16 bf16_t;
typedef __bf16 bf16x8 __attribute__((ext_vector_type(8)));
typedef float f32x4 __attribute__((ext_vector_type(4)));

#define MFMA16(a, b, c) __builtin_amdgcn_mfma_f32_16x16x32_bf16(a, b, c, 0, 0, 0)

__device__ __forceinline__ void gload_lds16(const bf16_t* g, bf16_t* l) {
  __builtin_amdgcn_global_load_lds(
      (const __attribute__((address_space(1))) void*)g,
      (__attribute__((address_space(3))) void*)l, 16, 0, 0);
}

__device__ __forceinline__ int sw4(int i) {  // nibble swap of 0..15
  return ((i & 3) << 2) | ((i >> 2) & 3);
}

// ---------------------------------------------------------------------------
// Transpose+convert both weights in one launch. blocks 0..767: qkv_w [256,768];
// blocks 768..1023: proj_w [256,256].
__global__ __launch_bounds__(256) void cvt_w2_k(const float* __restrict__ w1,
                                                bf16_t* __restrict__ o1,
                                                const float* __restrict__ w2,
                                                bf16_t* __restrict__ o2) {
  int blk = blockIdx.x, k = threadIdx.x;
  if (blk < 768) {
    o1[(size_t)blk * 256 + k] = (bf16_t)w1[(size_t)k * 768 + blk];
  } else {
    int n = blk - 768;
    o2[(size_t)n * 256 + k] = (bf16_t)w2[(size_t)k * 256 + n];
  }
}

// ---------------------------------------------------------------------------
// GEMM: C[M, ncols-slice] = A[M,256] @ B  with BT[n][k] pre-transposed bf16.
// AF32: A is fp32; staged via registers (load f32 -> cvt bf16 -> ds_write to
// the same swizzled sA layout). This fuses the old cvt_x pass into gemm1,
// removing 308MB of HBM traffic (205R+103W).
// XCD chunk-swizzle (bijective, nwg%8==0): XCD x computes a contiguous run of
// tile-space; runs of gridDim.x consecutive tiles share one A panel -> L2 hit.
template <bool AF32>
__global__ __launch_bounds__(256) void gemm256_t(const void* __restrict__ Av,
                                                 const bf16_t* __restrict__ BT,
                                                 int ncols,
                                                 bf16_t* __restrict__ outb,
                                                 float* __restrict__ outf,
                                                 const float* __restrict__ bias) {
  __shared__ __align__(16) bf16_t sA[128 * 64];
  __shared__ __align__(16) bf16_t sB[128 * 64];
  const int tid = threadIdx.x;
  const int lane = tid & 63, wave = tid >> 6;
  const int lm = lane & 15, quad = lane >> 4;

  int nwg = gridDim.x * gridDim.y;
  int L = blockIdx.y * gridDim.x + blockIdx.x;
  if ((nwg & 7) == 0) {
    int cpx = nwg >> 3;
    L = (L & 7) * cpx + (L >> 3);
  }
  const int bx = L % gridDim.x, by = L / gridDim.x;

  const int mBase = by * 128;
  const int nBase = bx * 128;
  const int wm = (wave >> 1) * 64, wn = (wave & 1) * 64;

  f32x4 acc[4][4];
#pragma unroll
  for (int i = 0; i < 4; i++)
#pragma unroll
    for (int j = 0; j < 4; j++) acc[i][j] = {0.f, 0.f, 0.f, 0.f};

  const bf16_t* Ab = AF32 ? nullptr : (const bf16_t*)Av + (size_t)mBase * 256;
  const float* Af = AF32 ? (const float*)Av + (size_t)mBase * 256 : nullptr;
  const bf16_t* Bb = BT + (size_t)nBase * 256;

  for (int kb = 0; kb < 4; ++kb) {
    const int k0 = kb * 64;
    if constexpr (AF32) {
      // A: reg-staged fp32 -> bf16. Same final sA layout as the LDS-DMA path
      // (lane's 16B lands at sA + cid*8).
      f32x4 fa[4][2];
#pragma unroll
      for (int it = 0; it < 4; ++it) {
        int cid = it * 256 + wave * 64 + lane;
        int row = cid >> 3, kcp = cid & 7;
        int kcl = kcp ^ (row & 7);
        const f32x4* src = (const f32x4*)(Af + (size_t)row * 256 + k0 + kcl * 8);
        fa[it][0] = src[0];
        fa[it][1] = src[1];
      }
#pragma unroll
      for (int it = 0; it < 4; ++it) {
        int cid = it * 256 + wave * 64 + lane;
        int row = cid >> 3, kcp = cid & 7;
        bf16_t* dstB = sB + (it * 256 + wave * 64) * 8;
        gload_lds16(Bb + (size_t)row * 256 + k0 + (kcp ^ (row & 7)) * 8, dstB);
        bf16x8 o = {(bf16_t)fa[it][0][0], (bf16_t)fa[it][0][1],
                    (bf16_t)fa[it][0][2], (bf16_t)fa[it][0][3],
                    (bf16_t)fa[it][1][0], (bf16_t)fa[it][1][1],
                    (bf16_t)fa[it][1][2], (bf16_t)fa[it][1][3]};
        *(bf16x8*)(sA + (size_t)cid * 8) = o;
      }
    } else {
#pragma unroll
      for (int it = 0; it < 4; ++it) {
        int cid = it * 256 + wave * 64 + lane;
        int row = cid >> 3, kcp = cid & 7;
        int kcl = kcp ^ (row & 7);
        bf16_t* dstA = sA + (it * 256 + wave * 64) * 8;  // wave-uniform base
        bf16_t* dstB = sB + (it * 256 + wave * 64) * 8;
        gload_lds16(Ab + (size_t)row * 256 + k0 + kcl * 8, dstA);
        gload_lds16(Bb + (size_t)row * 256 + k0 + kcl * 8, dstB);
      }
    }
    __syncthreads();
#pragma unroll
    for (int kk = 0; kk < 64; kk += 32) {
      int c = (kk >> 3) + quad;
      bf16x8 af[4], bfr[4];
#pragma unroll
      for (int mt = 0; mt < 4; mt++) {
        int m = wm + mt * 16 + lm;
        af[mt] = *(const bf16x8*)(sA + m * 64 + ((c ^ (m & 7)) << 3));
      }
#pragma unroll
      for (int nt = 0; nt < 4; nt++) {
        int n = wn + nt * 16 + lm;
        bfr[nt] = *(const bf16x8*)(sB + n * 64 + ((c ^ (n & 7)) << 3));
      }
#pragma unroll
      for (int mt = 0; mt < 4; mt++)
#pragma unroll
        for (int nt = 0; nt < 4; nt++)
          acc[mt][nt] = MFMA16(af[mt], bfr[nt], acc[mt][nt]);
    }
    __syncthreads();
  }

  if (outb) {
#pragma unroll
    for (int mt = 0; mt < 4; mt++)
#pragma unroll
      for (int nt = 0; nt < 4; nt++) {
        int col = nBase + wn + nt * 16 + lm;
        int rbase = mBase + wm + mt * 16 + quad * 4;
#pragma unroll
        for (int r = 0; r < 4; r++)
          outb[(size_t)(rbase + r) * ncols + col] = (bf16_t)acc[mt][nt][r];
      }
  } else {
#pragma unroll
    for (int mt = 0; mt < 4; mt++)
#pragma unroll
      for (int nt = 0; nt < 4; nt++) {
        int col = nBase + wn + nt * 16 + lm;
        float bv = bias[col];
        int rbase = mBase + wm + mt * 16 + quad * 4;
#pragma unroll
        for (int r = 0; r < 4; r++)
          outf[(size_t)(rbase + r) * ncols + col] = acc[mt][nt][r] + bv;
      }
  }
}

// ---------------------------------------------------------------------------
// Fused window attention, v6 = round-0 body (256 threads, one head per block,
// register-resident S, wave-parallel softmax, swizzled LDS P/VT) with ONE
// change: the (b,h) decode. Grid is 1D 16384; L = qd*16 + g*8 + x maps to
// bidx = qd*8+x, b = bidx>>2, h = (bidx&3)*2 + g. Sibling heads (2p, 2p+1)
// share every 128B qkv line (head h owns bytes [h*64, h*64+64) of each 512B
// q/k/v segment); this decode gives both L%8 = x (same XCD) at dispatch
// distance 8 (co-resident) -> each qkv line fetched from HBM once, not twice.
__global__ __launch_bounds__(256, 4) void attn_win(
    const bf16_t* __restrict__ qkv, const float* __restrict__ mask,
    const float* __restrict__ btab, bf16_t* __restrict__ y) {
  __shared__ __align__(16) bf16_t sP[112 * 128];
  __shared__ __align__(16) bf16_t sVT[32 * 128];
  __shared__ float sTab[512];
  __shared__ int sU[112];

  const int tid = threadIdx.x;
  const int L = blockIdx.x;
  const int qd = L >> 4, rr = L & 15;
  const int g = rr >> 3, x = rr & 7;
  const int bidx = qd * 8 + x;
  const int b = bidx >> 2;
  const int h = ((bidx & 3) << 1) | g;
  const int lane = tid & 63, wave = tid >> 6;
  const int lm = lane & 15, quad = lane >> 4;

  // ---- phase A: zero P (for K-pad cols 112..127), bias table, u[], VT ----
  {
    uint4 z = {0, 0, 0, 0};
    uint4* p = (uint4*)sP;
    for (int i = tid; i < 112 * 128 / 8; i += 256) p[i] = z;
  }
  // zero VT pad cols j in [98,128) (disjoint from staged j<98: no race)
  for (int idx = tid; idx < 1024; idx += 256) {
    int d = idx >> 5, j = 96 + (idx & 31);
    if (j >= 98)
      sVT[d * 128 + (((j >> 3) ^ sw4(d & 15)) << 3) + (j & 7)] = (bf16_t)0.f;
  }
  for (int i = tid; i < 507; i += 256) sTab[i] = btab[i * 8 + h];
  if (tid < 112) {
    int n = tid;
    int d = n / 49, r = n - d * 49;
    int hh = r / 7, w = r - hh * 7;
    sU[tid] = (n < 98) ? (d * 169 + hh * 13 + w) : 0;
  }

  const bf16_t* qb = qkv + (size_t)b * 98 * 768 + h * 32;

  // VT stage: thread (j = tid&127 < 98, hf = tid>>7) handles dc = hf, hf+2
  {
    int j = tid & 127, hf = tid >> 7;
    if (j < 98) {
#pragma unroll
      for (int t = 0; t < 2; t++) {
        int dc = hf + 2 * t;
        bf16x8 v8 = *(const bf16x8*)(qb + (size_t)j * 768 + 512 + dc * 8);
#pragma unroll
        for (int e = 0; e < 8; e++) {
          int d = dc * 8 + e;
          sVT[d * 128 + (((j >> 3) ^ sw4(d & 15)) << 3) + (j & 7)] = v8[e];
        }
      }
    }
  }
  __syncthreads();

  // ---- QK^T: wave computes row-tiles rt = wave, wave+4 ----
  bf16x8 kf[7];
#pragma unroll
  for (int ct = 0; ct < 7; ct++)
    kf[ct] =
        *(const bf16x8*)(qb + (size_t)(ct * 16 + lm) * 768 + 256 + quad * 8);

  f32x4 s4[2][7];
#pragma unroll
  for (int rti = 0; rti < 2; rti++) {
    int rt = wave + rti * 4;
    if (rt <= 6) {
      bf16x8 qf = *(const bf16x8*)(qb + (size_t)(rt * 16 + lm) * 768 + quad * 8);
#pragma unroll
      for (int ct = 0; ct < 7; ct++) {
        f32x4 z = {0.f, 0.f, 0.f, 0.f};
        s4[rti][ct] = MFMA16(qf, kf[ct], z);
      }
    }
  }

  // ---- epilogue (scale+bias+mask), softmax, P store ----
  const float* mp = mask + (size_t)(b & 63) * 9604;
  const float scale = 0.17677669529663687f;
  float inv[2][4];

#pragma unroll
  for (int rti = 0; rti < 2; rti++) {
    int rt = wave + rti * 4;
    if (rt > 6) continue;
    int ib = rt * 16 + quad * 4;
    int ui[4], rb[4];
#pragma unroll
    for (int r = 0; r < 4; r++) {
      int i = ib + r;
      ui[r] = sU[i] + 253;
      rb[r] = (i < 98 ? i : 97) * 98;
    }
#pragma unroll
    for (int ct = 0; ct < 7; ct++) {
      int j = ct * 16 + lm;
      int uj = sU[j];
      int jc = j < 98 ? j : 97;
      bool jv = j < 98;
#pragma unroll
      for (int r = 0; r < 4; r++) {
        float v = s4[rti][ct][r] * scale + sTab[ui[r] - uj] + mp[rb[r] + jc];
        s4[rti][ct][r] = jv ? v : -1e30f;
      }
    }
#pragma unroll
    for (int r = 0; r < 4; r++) {
      float mx = s4[rti][0][r];
#pragma unroll
      for (int ct = 1; ct < 7; ct++) mx = fmaxf(mx, s4[rti][ct][r]);
#pragma unroll
      for (int o = 1; o < 16; o <<= 1) mx = fmaxf(mx, __shfl_xor(mx, o));
      float sum = 0.f;
#pragma unroll
      for (int ct = 0; ct < 7; ct++) {
        float e = __expf(s4[rti][ct][r] - mx);
        s4[rti][ct][r] = e;
        sum += e;
      }
#pragma unroll
      for (int o = 1; o < 16; o <<= 1) sum += __shfl_xor(sum, o);
      inv[rti][r] = 1.f / sum;
    }
    // store P bf16, swizzled: conflict-free column-wise stores
#pragma unroll
    for (int ct = 0; ct < 7; ct++) {
      int c2 = 2 * ct + (lm >> 3);
      int j7 = lm & 7;
#pragma unroll
      for (int r = 0; r < 4; r++) {
        int i = ib + r;
        sP[i * 128 + ((c2 ^ (4 * r + quad)) << 3) + j7] =
            (bf16_t)s4[rti][ct][r];
      }
    }
  }
  __syncthreads();

  // ---- O = P V (K padded to 128 with zero P cols), scale by 1/sum ----
  bf16x8 vf[2][4];
#pragma unroll
  for (int dt = 0; dt < 2; dt++)
#pragma unroll
    for (int kk = 0; kk < 4; kk++) {
      int d = dt * 16 + lm;
      vf[dt][kk] =
          *(const bf16x8*)(sVT + d * 128 + (((4 * kk + quad) ^ sw4(lm)) << 3));
    }
  bf16_t* yb = y + (size_t)b * 98 * 256 + h * 32;
#pragma unroll
  for (int rti = 0; rti < 2; rti++) {
    int rt = wave + rti * 4;
    if (rt > 6) continue;
    bf16x8 af[4];
#pragma unroll
    for (int kk = 0; kk < 4; kk++) {
      int i = rt * 16 + lm;
      af[kk] =
          *(const bf16x8*)(sP + i * 128 + (((4 * kk + quad) ^ sw4(lm)) << 3));
    }
#pragma unroll
    for (int dt = 0; dt < 2; dt++) {
      f32x4 o = {0.f, 0.f, 0.f, 0.f};
#pragma unroll
      for (int kk = 0; kk < 4; kk++) o = MFMA16(af[kk], vf[dt][kk], o);
#pragma unroll
      for (int r = 0; r < 4; r++) {
        int i = rt * 16 + quad * 4 + r;
        if (i < 98)
          yb[(size_t)i * 256 + dt * 16 + lm] = (bf16_t)(o[r] * inv[rti][r]);
      }
    }
  }
}

// ---------------------------------------------------------------------------
extern "C" void kernel_launch(void* const* d_in, const int* in_sizes, int n_in,
                              void* d_out, int out_size, void* d_ws,
                              size_t ws_size, hipStream_t stream) {
  const float* x = (const float*)d_in[0];       // [2048, 98, 256]
  const float* mask = (const float*)d_in[1];    // [64, 98, 98]
  const float* qkv_w = (const float*)d_in[2];   // [256, 768]
  const float* proj_w = (const float*)d_in[3];  // [256, 256]
  const float* proj_b = (const float*)d_in[4];  // [256]
  const float* btab = (const float*)d_in[5];    // [507, 8]
  float* out = (float*)d_out;                   // [2048, 98, 256]

  char* ws = (char*)d_ws;
  bf16_t* qkv = (bf16_t*)ws;
  bf16_t* ybuf = (bf16_t*)(ws + 308281344);
  bf16_t* wT = (bf16_t*)(ws + 308281344 + 102760448);
  bf16_t* pT = (bf16_t*)(ws + 308281344 + 102760448 + 393216);

  cvt_w2_k<<<1024, 256, 0, stream>>>(qkv_w, wT, proj_w, pT);

  // gemm1: A = x (fp32, converted in-kernel), writes qkv bf16
  gemm256_t<true><<<dim3(6, 1568), 256, 0, stream>>>(x, wT, 768, qkv, nullptr,
                                                     nullptr);

  attn_win<<<16384, 256, 0, stream>>>(qkv, mask, btab, ybuf);

  // gemm2: A = ybuf (bf16), writes out fp32 + bias
  gemm256_t<false><<<dim3(2, 1568), 256, 0, stream>>>(ybuf, pT, 256, nullptr,
                                                      out, proj_b);
}